// Round 5
// baseline (240.316 us; speedup 1.0000x reference)
//
#include <hip/hip_runtime.h>

// bMomentumLIF forward: x[B,T,F] fp32 -> spikes[B,T,F] fp32
// Per-neuron recurrence (TAU=2):
//   u  = u_last*0.5 + x[t]; s = (u-th>=0); m = mt*m + (1-mt)*(u-u_last);
//   u' = (u*lb + m*(1-lb))*(1-s)
//
// R2/R4: 80 us pinned @ ~3.3 TB/s effective regardless of ring depth / NT /
// L3-vs-HBM source. Theory: lockstep-t address camping — at any instant the
// grid touches 64 x 32KB stripes at exactly 2 MiB stride, exercising only a
// small subset of channel-interleave bits (same bits for HBM and L3 slices).
// R5: phase-stagger S=4 neuron groups per thread at t offsets of 16 so four
// different t-slabs are live simultaneously -> 4x channel diversity.

constexpr int B = 64;
constexpr int T = 64;
constexpr int F = 8192;
constexpr int S   = 4;    // stagger groups per thread
constexpr int DLT = 16;   // t-phase offset between groups

template <int GLO, int GHI>
__device__ __forceinline__ void run_phase(
    int tau0, const int* base, float* u, float* m,
    const float* __restrict__ x, float* __restrict__ out,
    float mt, float omt, float lb, float olb, float th)
{
    // No FMA contraction: spike threshold is an exact compare vs the numpy
    // fp32 reference; contraction can flip boundary spikes (R1 bit-exact).
#pragma clang fp contract(off)
#pragma unroll
    for (int k = 0; k < DLT; ++k) {
        const int tau = tau0 + k;
#pragma unroll
        for (int g = GLO; g <= GHI; ++g) {
            const int t   = tau - DLT * g;
            const int idx = base[g] + t * F;
            const float xv = x[idx];
            const float uu = u[g] * 0.5f + xv;
            const float s  = ((uu - th) >= 0.0f) ? 1.0f : 0.0f;
            const float a  = mt * m[g];
            const float bq = omt * (uu - u[g]);
            m[g] = a + bq;
            u[g] = (uu * lb + m[g] * olb) * (1.0f - s);
            __builtin_nontemporal_store(s, &out[idx]);
        }
    }
}

__global__ __launch_bounds__(256) void lif_fwd_kernel(
    const float* __restrict__ x,
    const float* __restrict__ momentum,
    const float* __restrict__ lamb,
    const float* __restrict__ thresholds,
    float*       __restrict__ out)
{
#pragma clang fp contract(off)
    const int tid = blockIdx.x * blockDim.x + threadIdx.x;  // 0 .. B*F/S-1
    const int b0  = tid >> 13;          // F = 8192 -> 13 bits; b0 in [0,16)
    const int f   = tid & (F - 1);

    const float mt  = momentum[0];
    const float omt = 1.0f - mt;
    const float lb  = lamb[0];
    const float olb = 1.0f - lb;
    const float th  = thresholds[0];

    int   base[S];
    float u[S], m[S];
#pragma unroll
    for (int g = 0; g < S; ++g) {
        base[g] = (b0 + 16 * g) * (T * F) + f;  // group g owns b = b0 + 16g
        u[g] = 0.0f;
        m[g] = 0.0f;
    }

    // Phase p covers tau in [16p, 16p+16); group g active iff g<=p<=g+3.
    run_phase<0, 0>(  0, base, u, m, x, out, mt, omt, lb, olb, th);
    run_phase<0, 1>( 16, base, u, m, x, out, mt, omt, lb, olb, th);
    run_phase<0, 2>( 32, base, u, m, x, out, mt, omt, lb, olb, th);
    run_phase<0, 3>( 48, base, u, m, x, out, mt, omt, lb, olb, th);
    run_phase<1, 3>( 64, base, u, m, x, out, mt, omt, lb, olb, th);
    run_phase<2, 3>( 80, base, u, m, x, out, mt, omt, lb, olb, th);
    run_phase<3, 3>( 96, base, u, m, x, out, mt, omt, lb, olb, th);
}

extern "C" void kernel_launch(void* const* d_in, const int* in_sizes, int n_in,
                              void* d_out, int out_size, void* d_ws, size_t ws_size,
                              hipStream_t stream) {
    const float* x   = (const float*)d_in[0];
    const float* mom = (const float*)d_in[1];
    const float* lmb = (const float*)d_in[2];
    const float* thr = (const float*)d_in[3];
    float* out = (float*)d_out;

    const int n_threads = B * F / S;       // 131072
    const int block = 256;
    const int grid = n_threads / block;    // 512
    lif_fwd_kernel<<<grid, block, 0, stream>>>(x, mom, lmb, thr, out);
}

// Round 6
// 238.207 us; speedup vs baseline: 1.0089x; 1.0089x over previous
//
#include <hip/hip_runtime.h>

// bMomentumLIF forward: x[B,T,F] fp32 -> spikes[B,T,F] fp32
// Per-neuron recurrence (TAU=2):
//   u  = u_last*0.5 + x[t]; s = (u-th>=0); m = mt*m + (1-mt)*(u-u_last);
//   u' = (u*lb + m*(1-lb))*(1-s)
//
// History: R1 float4 236us bench; R2 float2/ring4 kernel 80us; R4 +NT stores
// 81us (reads fully L3-hit, STILL 81us -> HBM exonerated); R5 phase-stagger
// 82us (camping theory dead). All variants: 8-16 waves/CU, VALUBusy ~16%,
// ~84% of cycles = memory-latency stalls. Diagnosis: latency x insufficient
// outstanding requests.
// R6: (a) scalar neuron/thread -> 8192 waves = 32 waves/CU (100% occupancy,
// VGPR<=64); (b) explicit 8-deep register prefetch ring -> 64KB/CU in
// flight; (c) burst stores every 8 steps so in-order vmcnt load-waits don't
// queue behind per-iteration stores.

constexpr int B = 64;
constexpr int T = 64;
constexpr int F = 8192;
constexpr int P = 8;      // prefetch ring depth == store burst length

__global__ __launch_bounds__(256) void lif_fwd_kernel(
    const float* __restrict__ x,
    const float* __restrict__ momentum,
    const float* __restrict__ lamb,
    const float* __restrict__ thresholds,
    float*       __restrict__ out)
{
    // No FMA contraction: spike threshold is an exact compare vs the numpy
    // fp32 reference; contraction can flip boundary spikes (R1-R5 bit-exact
    // with this exact op order).
#pragma clang fp contract(off)

    const int tid = blockIdx.x * blockDim.x + threadIdx.x;  // 0 .. B*F-1
    const int b   = tid >> 13;          // F = 8192
    const int f   = tid & (F - 1);

    const float mt  = momentum[0];
    const float omt = 1.0f - mt;
    const float lb  = lamb[0];
    const float olb = 1.0f - lb;
    const float th  = thresholds[0];

    const int base = b * (T * F) + f;   // element index; stride F per step

    // Prime: P loads in flight before any compute.
    float buf[P];
#pragma unroll
    for (int i = 0; i < P; ++i) buf[i] = x[base + i * F];

    float u = 0.0f, m = 0.0f;

#pragma unroll
    for (int c = 0; c < T / P; ++c) {
        float sv[P];
#pragma unroll
        for (int j = 0; j < P; ++j) {
            const int t = c * P + j;
            const float xv = buf[j];
            // Refill this slot immediately (t+P), BEFORE this chunk's
            // stores are issued, so the wait to consume it next chunk sits
            // behind loads only (in-order vmcnt).
            if (t + P < T) buf[j] = x[base + (t + P) * F];

            const float uu = u * 0.5f + xv;
            const float s  = ((uu - th) >= 0.0f) ? 1.0f : 0.0f;
            const float a  = mt * m;
            const float bq = omt * (uu - u);
            m = a + bq;
            u = (uu * lb + m * olb) * (1.0f - s);
            sv[j] = s;
        }
        // Burst the chunk's stores (write-once output, nontemporal).
#pragma unroll
        for (int j = 0; j < P; ++j) {
            __builtin_nontemporal_store(sv[j], &out[base + (c * P + j) * F]);
        }
    }
}

extern "C" void kernel_launch(void* const* d_in, const int* in_sizes, int n_in,
                              void* d_out, int out_size, void* d_ws, size_t ws_size,
                              hipStream_t stream) {
    const float* x   = (const float*)d_in[0];
    const float* mom = (const float*)d_in[1];
    const float* lmb = (const float*)d_in[2];
    const float* thr = (const float*)d_in[3];
    float* out = (float*)d_out;

    const int n_threads = B * F;           // 524288
    const int block = 256;
    const int grid = n_threads / block;    // 2048 blocks -> 32 waves/CU
    lif_fwd_kernel<<<grid, block, 0, stream>>>(x, mom, lmb, thr, out);
}